// Round 16
// baseline (84.343 us; speedup 1.0000x reference)
//
#include <hip/hip_runtime.h>
#include <math.h>

#define DIM    512
#define RANK   4
#define NROW   2048   // BATCH * SEQ
#define DH     64
#define NH     16384  // NROW * HEADS
#define EPS    1e-8f
#define EPSDEN2 2.68435456f   // EPS * NH^2 (den ~= NH; measure-cancellation, r3)
// y = s*(1+lam)/16, lam = 1/512 (minimax absorb of x^3/6), w = 1 + 2y + 2y^2
#define KSCALE 0.0626220703125f
#define C1 (2.0f * KSCALE)            // scale on M1
#define C2 (2.0f * KSCALE * KSCALE)   // scale on T2
#define KSPL 32                       // phase-A key splits (512 keys each)

typedef short    bf16x8 __attribute__((ext_vector_type(8)));
typedef ushort   u16x8  __attribute__((ext_vector_type(8)));
typedef _Float16 half8  __attribute__((ext_vector_type(8)));
typedef float    f32x16 __attribute__((ext_vector_type(16)));

static __device__ __forceinline__ ushort f2bf(float f) {
    uint u = __float_as_uint(f);
    u += 0x7FFFu + ((u >> 16) & 1u);
    return (ushort)(u >> 16);
}
static __device__ __forceinline__ float bf2f(ushort u) {
    return __uint_as_float((uint)u << 16);
}
static __device__ __forceinline__ uint pkh2(float a, float b) {
    _Float16 ha = (_Float16)a, hb = (_Float16)b;
    return (uint)__builtin_bit_cast(ushort, ha) | ((uint)__builtin_bit_cast(ushort, hb) << 16);
}
static __device__ __forceinline__ float h2f(ushort u) {
    return (float)__builtin_bit_cast(_Float16, u);
}
static __device__ __forceinline__ void barrier_lgkm() {
    asm volatile("s_waitcnt lgkmcnt(0)" ::: "memory");
    __builtin_amdgcn_s_barrier();
}

// ---------------------------------------------------------------------------
// Kernel 1: TT projections q,k,v + L2-normalize q,k per head-row.
// r16: 8 rows per block (grid 256); A/B/bias slices hoisted to registers
// (row-invariant, statically indexed). Inner body identical to r15-verified.
// Outputs: qq_b bf16 [NH][64]; kqT f16 [64][NH]; vvT f16 [64][NH].
// ---------------------------------------------------------------------------
__global__ __launch_bounds__(256) void proj_qkv(
    const float* __restrict__ x,
    const float* __restrict__ qA, const float* __restrict__ qB, const float* __restrict__ qb,
    const float* __restrict__ kA, const float* __restrict__ kB, const float* __restrict__ kb,
    const float* __restrict__ vA, const float* __restrict__ vB, const float* __restrict__ vb,
    ushort* __restrict__ qq_b, ushort* __restrict__ kqT, ushort* __restrict__ vvT)
{
    __shared__ float qrow[DIM], krow[DIM], vrowS[DIM];
    __shared__ float wred[4][12];
    __shared__ float tvals[12];
    __shared__ float norms[16];

    const int t = threadIdx.x;
    const int wid = t >> 6, lane = t & 63;

    // hoisted per-thread weight slices (row-invariant)
    float Bq[4][2], Bk[4][2], Bv[4][2];
    #pragma unroll
    for (int r = 0; r < 4; ++r) {
        Bq[r][0] = qB[r * DIM + t]; Bq[r][1] = qB[r * DIM + t + 256];
        Bk[r][0] = kB[r * DIM + t]; Bk[r][1] = kB[r * DIM + t + 256];
        Bv[r][0] = vB[r * DIM + t]; Bv[r][1] = vB[r * DIM + t + 256];
    }
    float Aq[2][4], Ak[2][4], Av[2][4], biasq[2], biask[2], biasv[2];
    #pragma unroll
    for (int h = 0; h < 2; ++h) {
        const int o = t + h * 256;
        biasq[h] = qb[o]; biask[h] = kb[o]; biasv[h] = vb[o];
        #pragma unroll
        for (int r = 0; r < 4; ++r) {
            Aq[h][r] = qA[o * RANK + r];
            Ak[h][r] = kA[o * RANK + r];
            Av[h][r] = vA[o * RANK + r];
        }
    }

    for (int i = 0; i < 8; ++i) {
        const int n = blockIdx.x * 8 + i;

        const float x0 = x[n * DIM + t];
        const float x1 = x[n * DIM + t + 256];

        float p[12];
        #pragma unroll
        for (int r = 0; r < 4; ++r) {
            p[r]     = x0 * Bq[r][0] + x1 * Bq[r][1];
            p[4 + r] = x0 * Bk[r][0] + x1 * Bk[r][1];
            p[8 + r] = x0 * Bv[r][0] + x1 * Bv[r][1];
        }
        #pragma unroll
        for (int j = 0; j < 12; ++j) {
            #pragma unroll
            for (int off = 32; off; off >>= 1) p[j] += __shfl_xor(p[j], off);
        }
        if (lane == 0) {
            #pragma unroll
            for (int j = 0; j < 12; ++j) wred[wid][j] = p[j];
        }
        __syncthreads();
        if (t < 12) tvals[t] = wred[0][t] + wred[1][t] + wred[2][t] + wred[3][t];
        __syncthreads();

        float tq[4], tk[4], tv[4];
        #pragma unroll
        for (int r = 0; r < 4; ++r) { tq[r] = tvals[r]; tk[r] = tvals[4 + r]; tv[r] = tvals[8 + r]; }

        #pragma unroll
        for (int h = 0; h < 2; ++h) {
            const int o = t + h * 256;
            float yq = biasq[h], yk = biask[h], yv = biasv[h];
            #pragma unroll
            for (int r = 0; r < 4; ++r) {
                yq += tq[r] * Aq[h][r];
                yk += tk[r] * Ak[h][r];
                yv += tv[r] * Av[h][r];
            }
            qrow[o] = yq; krow[o] = yk; vrowS[o] = yv;
        }
        __syncthreads();

        {
            const int c = t >> 5, i2 = t & 31;
            const float a  = qrow[c * 64 + i2], b2 = qrow[c * 64 + i2 + 32];
            const float ak = krow[c * 64 + i2], bk = krow[c * 64 + i2 + 32];
            float s  = a * a + b2 * b2;
            float sk = ak * ak + bk * bk;
            #pragma unroll
            for (int off = 16; off; off >>= 1) { s += __shfl_xor(s, off); sk += __shfl_xor(sk, off); }
            if (i2 == 0) { norms[c] = sqrtf(s); norms[8 + c] = sqrtf(sk); }
        }
        __syncthreads();

        #pragma unroll
        for (int h = 0; h < 2; ++h) {
            const int o = t + h * 256;
            const int c = o >> 6;
            qq_b[n * DIM + o] = f2bf(qrow[o] / (norms[c] + EPS));
        }

        // transposes: kqT[d][n*8+j] = khat, vvT[d][n*8+j] = v  (f16)
        if (t < 64) {
            uint pk[4], pv[4];
            #pragma unroll
            for (int j = 0; j < 4; ++j) {
                const float k0 = krow[(2 * j) * 64 + t]     / (norms[8 + 2 * j] + EPS);
                const float k1 = krow[(2 * j + 1) * 64 + t] / (norms[8 + 2 * j + 1] + EPS);
                pk[j] = pkh2(k0, k1);
                pv[j] = pkh2(vrowS[(2 * j) * 64 + t], vrowS[(2 * j + 1) * 64 + t]);
            }
            uint4 uk; uk.x = pk[0]; uk.y = pk[1]; uk.z = pk[2]; uk.w = pk[3];
            uint4 uv; uv.x = pv[0]; uv.y = pv[1]; uv.z = pv[2]; uv.w = pv[3];
            *(uint4*)((char*)kqT + (size_t)t * (NH * 2) + (size_t)n * 16) = uk;
            *(uint4*)((char*)vvT + (size_t)t * (NH * 2) + (size_t)n * 16) = uv;
        }
        // next iteration's first LDS write is ordered by the step-1 syncs
    }
}

// ---------------------------------------------------------------------------
// Kernel 2 (phase A): moment tensors; M1 fused into agroup0/wave0.
// (identical to r15, verified)
// ---------------------------------------------------------------------------
__global__ __launch_bounds__(256, 2) void phaseA(
    const ushort* __restrict__ kqT, const ushort* __restrict__ vvT,
    ushort* __restrict__ partA, ushort* __restrict__ partM1)
{
    __shared__ __align__(16) char smem[2][10240];   // [buf][ K 5120 | V 5120 ]
    constexpr int NSTA = 16;                        // 512 keys / 32

    const int t = threadIdx.x;
    const int w = t >> 6, l = t & 63;
    const int l31 = l & 31, hi = l >> 5;
    const int agroup = blockIdx.x >> 5;             // 0..15
    const int ksplit = blockIdx.x & 31;
    const int kbase = ksplit * 512;
    const int a = agroup * 4 + w;
    const bool doM1 = (agroup == 0) && (w == 0);

    const int srow = t >> 2, sslot = t & 3;
    const int woff = srow * 80 + sslot * 16;
    const size_t go = (size_t)srow * NH + kbase + sslot * 8;

    f32x16 acc[2][2], accM[2][2];
    #pragma unroll
    for (int bt = 0; bt < 2; ++bt)
        #pragma unroll
        for (int dt = 0; dt < 2; ++dt)
            #pragma unroll
            for (int r = 0; r < 16; ++r) { acc[bt][dt][r] = 0.f; accM[bt][dt][r] = 0.f; }

    uint4 kst = *(const uint4*)(kqT + go);
    uint4 vst = *(const uint4*)(vvT + go);
    *(uint4*)(smem[0] + woff) = kst;
    *(uint4*)(smem[0] + 5120 + woff) = vst;
    kst = *(const uint4*)(kqT + go + 32);
    vst = *(const uint4*)(vvT + go + 32);
    barrier_lgkm();

    for (int s = 0; s < NSTA; ++s) {
        const char* B = smem[s & 1];
        if (s + 1 < NSTA) {
            char* D = (char*)smem[(s & 1) ^ 1];
            *(uint4*)(D + woff) = kst;
            *(uint4*)(D + 5120 + woff) = vst;
        }
        if (s + 2 < NSTA) {
            kst = *(const uint4*)(kqT + go + (size_t)(s + 2) * 32);
            vst = *(const uint4*)(vvT + go + (size_t)(s + 2) * 32);
        }

        half8 kraw[2][2], af[2][2], vf[2][2];
        const half8 bc0 = *(const half8*)(B + a * 80 + hi * 16);
        const half8 bc1 = *(const half8*)(B + a * 80 + 32 + hi * 16);
        #pragma unroll
        for (int bt = 0; bt < 2; ++bt) {
            kraw[bt][0] = *(const half8*)(B + (bt * 32 + l31) * 80 + hi * 16);
            kraw[bt][1] = *(const half8*)(B + (bt * 32 + l31) * 80 + 32 + hi * 16);
            af[bt][0] = kraw[bt][0] * bc0;
            af[bt][1] = kraw[bt][1] * bc1;
        }
        #pragma unroll
        for (int dt = 0; dt < 2; ++dt) {
            vf[dt][0] = *(const half8*)(B + 5120 + (dt * 32 + l31) * 80 + hi * 16);
            vf[dt][1] = *(const half8*)(B + 5120 + (dt * 32 + l31) * 80 + 32 + hi * 16);
        }
        #pragma unroll
        for (int bt = 0; bt < 2; ++bt)
            #pragma unroll
            for (int dt = 0; dt < 2; ++dt) {
                acc[bt][dt] = __builtin_amdgcn_mfma_f32_32x32x16_f16(af[bt][0], vf[dt][0], acc[bt][dt], 0, 0, 0);
                acc[bt][dt] = __builtin_amdgcn_mfma_f32_32x32x16_f16(af[bt][1], vf[dt][1], acc[bt][dt], 0, 0, 0);
            }
        if (doM1) {
            #pragma unroll
            for (int bt = 0; bt < 2; ++bt)
                #pragma unroll
                for (int dt = 0; dt < 2; ++dt) {
                    accM[bt][dt] = __builtin_amdgcn_mfma_f32_32x32x16_f16(kraw[bt][0], vf[dt][0], accM[bt][dt], 0, 0, 0);
                    accM[bt][dt] = __builtin_amdgcn_mfma_f32_32x32x16_f16(kraw[bt][1], vf[dt][1], accM[bt][dt], 0, 0, 0);
                }
        }
        barrier_lgkm();
    }

    {
        ushort* dst = partA + ((size_t)(ksplit * 64 + a)) * 4096;
        #pragma unroll
        for (int bt = 0; bt < 2; ++bt)
            #pragma unroll
            for (int dt = 0; dt < 2; ++dt) {
                const int d = dt * 32 + l31;
                #pragma unroll
                for (int g = 0; g < 4; ++g) {
                    uint2 u2;
                    u2.x = pkh2(acc[bt][dt][4 * g],     acc[bt][dt][4 * g + 1]);
                    u2.y = pkh2(acc[bt][dt][4 * g + 2], acc[bt][dt][4 * g + 3]);
                    const int b0 = bt * 32 + 8 * g + 4 * hi;
                    *(uint2*)(dst + (size_t)d * 64 + b0) = u2;
                }
            }
    }
    if (doM1) {
        ushort* dstM = partM1 + (size_t)ksplit * 4096;
        #pragma unroll
        for (int bt = 0; bt < 2; ++bt)
            #pragma unroll
            for (int dt = 0; dt < 2; ++dt) {
                const int d = dt * 32 + l31;
                #pragma unroll
                for (int g = 0; g < 4; ++g) {
                    uint2 u2;
                    u2.x = pkh2(accM[bt][dt][4 * g],     accM[bt][dt][4 * g + 1]);
                    u2.y = pkh2(accM[bt][dt][4 * g + 2], accM[bt][dt][4 * g + 3]);
                    const int b0 = bt * 32 + 8 * g + 4 * hi;
                    *(uint2*)(dstM + (size_t)d * 64 + b0) = u2;
                }
            }
    }
}

// ---------------------------------------------------------------------------
// Kernel 3: parallel reduction of partials, uint4-granular.
// blocks 0..127: T2 (32768 uint4-columns, 1/thread, 32 unrolled 16B loads);
//   + Vpart trace at 8-lane granularity (owner: a in [b0, b0+8)).
// blocks 128..129: M1 (512 uint4-columns).
// Same arithmetic as r15's verified reduce_mom.
// ---------------------------------------------------------------------------
__global__ __launch_bounds__(256) void reduce_mom(
    const ushort* __restrict__ partA, const ushort* __restrict__ partM1,
    ushort* __restrict__ T2s, ushort* __restrict__ M1s, float* __restrict__ Vpart)
{
    const int blk = blockIdx.x, t = threadIdx.x;
    if (blk < 128) {
        const int g4 = blk * 256 + t;               // uint4 index (8 ushorts)
        const uint4* src = (const uint4*)partA;
        float s[8];
        #pragma unroll
        for (int j = 0; j < 8; ++j) s[j] = 0.f;
        #pragma unroll
        for (int ks = 0; ks < KSPL; ++ks) {
            const uint4 u = src[(size_t)ks * 32768 + g4];
            s[0] += h2f((ushort)(u.x & 0xffff)); s[1] += h2f((ushort)(u.x >> 16));
            s[2] += h2f((ushort)(u.y & 0xffff)); s[3] += h2f((ushort)(u.y >> 16));
            s[4] += h2f((ushort)(u.z & 0xffff)); s[5] += h2f((ushort)(u.z >> 16));
            s[6] += h2f((ushort)(u.w & 0xffff)); s[7] += h2f((ushort)(u.w >> 16));
        }
        uint4 o;
        o.x = (uint)f2bf(C2 * s[0]) | ((uint)f2bf(C2 * s[1]) << 16);
        o.y = (uint)f2bf(C2 * s[2]) | ((uint)f2bf(C2 * s[3]) << 16);
        o.z = (uint)f2bf(C2 * s[4]) | ((uint)f2bf(C2 * s[5]) << 16);
        o.w = (uint)f2bf(C2 * s[6]) | ((uint)f2bf(C2 * s[7]) << 16);
        ((uint4*)T2s)[g4] = o;
        // trace: Vsum contribution at flat index a*4096 + d*64 + b with b == a
        const int e0 = g4 * 8;
        const int a  = e0 >> 12;
        const int d  = (e0 >> 6) & 63;
        const int b0 = e0 & 63;
        if (a >= b0 && a < b0 + 8) Vpart[a * 64 + d] = s[a - b0];
    } else if (blk < 130) {
        const int g4 = (blk - 128) * 256 + t;       // 0..511
        const uint4* src = (const uint4*)partM1;
        float s[8];
        #pragma unroll
        for (int j = 0; j < 8; ++j) s[j] = 0.f;
        #pragma unroll
        for (int ks = 0; ks < KSPL; ++ks) {
            const uint4 u = src[(size_t)ks * 512 + g4];
            s[0] += h2f((ushort)(u.x & 0xffff)); s[1] += h2f((ushort)(u.x >> 16));
            s[2] += h2f((ushort)(u.y & 0xffff)); s[3] += h2f((ushort)(u.y >> 16));
            s[4] += h2f((ushort)(u.z & 0xffff)); s[5] += h2f((ushort)(u.z >> 16));
            s[6] += h2f((ushort)(u.w & 0xffff)); s[7] += h2f((ushort)(u.w >> 16));
        }
        uint4 o;
        o.x = (uint)f2bf(C1 * s[0]) | ((uint)f2bf(C1 * s[1]) << 16);
        o.y = (uint)f2bf(C1 * s[2]) | ((uint)f2bf(C1 * s[3]) << 16);
        o.z = (uint)f2bf(C1 * s[4]) | ((uint)f2bf(C1 * s[5]) << 16);
        o.w = (uint)f2bf(C1 * s[6]) | ((uint)f2bf(C1 * s[7]) << 16);
        ((uint4*)M1s)[g4] = o;
    }
}

// ---------------------------------------------------------------------------
// Kernel 4 (phase B, fused finalize): identical to r15, verified.
// ---------------------------------------------------------------------------
__global__ __launch_bounds__(256, 3) void phaseB(
    const ushort* __restrict__ qq_b, const ushort* __restrict__ T2s,
    const ushort* __restrict__ M1s, const float* __restrict__ Vpart,
    const float* __restrict__ oA, const float* __restrict__ oB,
    const float* __restrict__ ob, float* __restrict__ out)
{
    __shared__ float Lred[4][64][33];   // [wave][d][q] padded -> conflict-free
    __shared__ float anum[32][65];      // [q][d] measure values
    __shared__ float VsumL[64];

    const int t = threadIdx.x;
    const int w = t >> 6, l = t & 63;
    const int l31 = l & 31, hi = l >> 5;
    const int q0 = blockIdx.x * 32;
    const int n0 = q0 >> 3;             // first of 4 (b,s) rows

    if (w == 3) {
        float vs = 0.f;
        #pragma unroll
        for (int a2 = 0; a2 < 64; ++a2) vs += Vpart[a2 * 64 + l];
        VsumL[l] = vs;
    }

    bf16x8 Qf[4];
    #pragma unroll
    for (int w16 = 0; w16 < 4; ++w16)
        Qf[w16] = *(const bf16x8*)((const char*)qq_b
            + (size_t)(q0 + l31) * 128 + w16 * 32 + hi * 16);

    float sv[16];
    {
        const uint4 u0 = *(const uint4*)(qq_b + (size_t)(q0 + l31) * 64 + w * 16);
        const uint4 u1 = *(const uint4*)(qq_b + (size_t)(q0 + l31) * 64 + w * 16 + 8);
        sv[0] = bf2f((ushort)(u0.x & 0xffff)); sv[1] = bf2f((ushort)(u0.x >> 16));
        sv[2] = bf2f((ushort)(u0.y & 0xffff)); sv[3] = bf2f((ushort)(u0.y >> 16));
        sv[4] = bf2f((ushort)(u0.z & 0xffff)); sv[5] = bf2f((ushort)(u0.z >> 16));
        sv[6] = bf2f((ushort)(u0.w & 0xffff)); sv[7] = bf2f((ushort)(u0.w >> 16));
        sv[8]  = bf2f((ushort)(u1.x & 0xffff)); sv[9]  = bf2f((ushort)(u1.x >> 16));
        sv[10] = bf2f((ushort)(u1.y & 0xffff)); sv[11] = bf2f((ushort)(u1.y >> 16));
        sv[12] = bf2f((ushort)(u1.z & 0xffff)); sv[13] = bf2f((ushort)(u1.z >> 16));
        sv[14] = bf2f((ushort)(u1.w & 0xffff)); sv[15] = bf2f((ushort)(u1.w >> 16));
    }

    f32x16 acc[2];
    #pragma unroll
    for (int dt = 0; dt < 2; ++dt)
        #pragma unroll
        for (int r = 0; r < 16; ++r) acc[dt][r] = 0.f;

    #pragma unroll 2
    for (int ai = 0; ai < 16; ++ai) {
        const char* base = (const char*)(T2s + (size_t)(w * 16 + ai) * 4096);
        #pragma unroll
        for (int dt = 0; dt < 2; ++dt) {
            bf16x8 af[4];
            #pragma unroll
            for (int w16 = 0; w16 < 4; ++w16)
                af[w16] = *(const bf16x8*)(base + (dt * 32 + l31) * 128 + w16 * 32 + hi * 16);
            f32x16 st;
            #pragma unroll
            for (int r = 0; r < 16; ++r) st[r] = 0.f;
            #pragma unroll
            for (int w16 = 0; w16 < 4; ++w16)
                st = __builtin_amdgcn_mfma_f32_32x32x16_bf16(af[w16], Qf[w16], st, 0, 0, 0);
            #pragma unroll
            for (int r = 0; r < 16; ++r)
                acc[dt][r] = fmaf(sv[ai], st[r], acc[dt][r]);
        }
    }

    if (w == 0) {
        #pragma unroll
        for (int dt = 0; dt < 2; ++dt) {
            bf16x8 af[4];
            #pragma unroll
            for (int w16 = 0; w16 < 4; ++w16)
                af[w16] = *(const bf16x8*)((const char*)M1s + (dt * 32 + l31) * 128 + w16 * 32 + hi * 16);
            f32x16 st;
            #pragma unroll
            for (int r = 0; r < 16; ++r) st[r] = 0.f;
            #pragma unroll
            for (int w16 = 0; w16 < 4; ++w16)
                st = __builtin_amdgcn_mfma_f32_32x32x16_bf16(af[w16], Qf[w16], st, 0, 0, 0);
            #pragma unroll
            for (int r = 0; r < 16; ++r) acc[dt][r] += st[r];
        }
    }

    #pragma unroll
    for (int dt = 0; dt < 2; ++dt)
        #pragma unroll
        for (int r = 0; r < 16; ++r) {
            const int d = dt * 32 + 8 * (r >> 2) + 4 * hi + (r & 3);
            Lred[w][d][l31] = acc[dt][r];
        }
    __syncthreads();

    {
        const int q = t >> 3, db = (t & 7) * 8;
        float av[8];
        float ss = 0.f;
        #pragma unroll
        for (int i = 0; i < 8; ++i) {
            const int d = db + i;
            const float s = (Lred[0][d][q] + Lred[1][d][q])
                          + (Lred[2][d][q] + Lred[3][d][q]) + VsumL[d];
            av[i] = s;
            ss = fmaf(s, s, ss);
        }
        ss += __shfl_xor(ss, 1);
        ss += __shfl_xor(ss, 2);
        ss += __shfl_xor(ss, 4);
        const float inv = 1.f / (ss + EPSDEN2);
        #pragma unroll
        for (int i = 0; i < 8; ++i) anum[q][db + i] = av[i] * av[i] * inv;
    }
    __syncthreads();

    {
        float p0 = 0.f, p1 = 0.f, p2 = 0.f, p3 = 0.f;
        #pragma unroll
        for (int h2 = 0; h2 < 8; ++h2) {
            const int o = h2 * 64 + l;
            const float m = anum[w * 8 + h2][l];
            p0 = fmaf(m, oB[o],        p0);
            p1 = fmaf(m, oB[512 + o],  p1);
            p2 = fmaf(m, oB[1024 + o], p2);
            p3 = fmaf(m, oB[1536 + o], p3);
        }
        #pragma unroll
        for (int off = 32; off; off >>= 1) {
            p0 += __shfl_xor(p0, off);
            p1 += __shfl_xor(p1, off);
            p2 += __shfl_xor(p2, off);
            p3 += __shfl_xor(p3, off);
        }
        float* dstrow = out + (size_t)(n0 + w) * DIM;
        #pragma unroll
        for (int h2 = 0; h2 < 8; ++h2) {
            const int o = h2 * 64 + l;
            const float4 a4 = *(const float4*)(oA + o * RANK);
            dstrow[o] = ob[o] + p0 * a4.x + p1 * a4.y + p2 * a4.z + p3 * a4.w;
        }
    }
}

// ---------------------------------------------------------------------------
extern "C" void kernel_launch(void* const* d_in, const int* in_sizes, int n_in,
                              void* d_out, int out_size, void* d_ws, size_t ws_size,
                              hipStream_t stream) {
    const float* x  = (const float*)d_in[0];
    const float* qA = (const float*)d_in[1];
    const float* qB = (const float*)d_in[2];
    const float* qb = (const float*)d_in[3];
    const float* kA = (const float*)d_in[4];
    const float* kB = (const float*)d_in[5];
    const float* kb = (const float*)d_in[6];
    const float* vA = (const float*)d_in[7];
    const float* vB = (const float*)d_in[8];
    const float* vb = (const float*)d_in[9];
    const float* oA = (const float*)d_in[10];
    const float* oB = (const float*)d_in[11];
    const float* ob = (const float*)d_in[12];

    // ws: qq 2MB | kqT 2MB | vvT 2MB | T2s 512KB | M1s 8KB | partM1 256KB |
    //     Vpart 16KB | partA 16MB
    ushort* qq_b   = (ushort*)d_ws;
    ushort* kqT    = qq_b + (size_t)NH * DH;
    ushort* vvT    = kqT + (size_t)NH * DH;
    ushort* T2s    = vvT + (size_t)NH * DH;
    ushort* M1s    = T2s + (size_t)64 * 4096;
    ushort* partM1 = M1s + 4096;
    float*  Vpart  = (float*)(partM1 + (size_t)KSPL * 4096);
    ushort* partA  = (ushort*)(Vpart + 4096);

    float* out = (float*)d_out;

    proj_qkv<<<256, 256, 0, stream>>>(x, qA, qB, qb, kA, kB, kb, vA, vB, vb, qq_b, kqT, vvT);
    phaseA<<<512, 256, 0, stream>>>(kqT, vvT, partA, partM1);
    reduce_mom<<<130, 256, 0, stream>>>(partA, partM1, T2s, M1s, Vpart);
    phaseB<<<512, 256, 0, stream>>>(qq_b, T2s, M1s, Vpart, oA, oB, ob, out);
}

// Round 17
// 78.653 us; speedup vs baseline: 1.0724x; 1.0724x over previous
//
#include <hip/hip_runtime.h>
#include <math.h>

#define DIM    512
#define RANK   4
#define NROW   2048   // BATCH * SEQ
#define DH     64
#define NH     16384  // NROW * HEADS
#define EPS    1e-8f
#define EPSDEN2 2.68435456f   // EPS * NH^2 (den ~= NH; measure-cancellation, r3)
// y = s*(1+lam)/16, lam = 1/512 (minimax absorb of x^3/6), w = 1 + 2y + 2y^2
#define KSCALE 0.0626220703125f
#define C1 (2.0f * KSCALE)            // scale on M1
#define C2 (2.0f * KSCALE * KSCALE)   // scale on T2
#define KSPL 32                       // phase-A key splits (512 keys each)

typedef short    bf16x8 __attribute__((ext_vector_type(8)));
typedef ushort   u16x8  __attribute__((ext_vector_type(8)));
typedef _Float16 half8  __attribute__((ext_vector_type(8)));
typedef float    f32x16 __attribute__((ext_vector_type(16)));

static __device__ __forceinline__ ushort f2bf(float f) {
    uint u = __float_as_uint(f);
    u += 0x7FFFu + ((u >> 16) & 1u);
    return (ushort)(u >> 16);
}
static __device__ __forceinline__ float bf2f(ushort u) {
    return __uint_as_float((uint)u << 16);
}
static __device__ __forceinline__ uint pkh2(float a, float b) {
    _Float16 ha = (_Float16)a, hb = (_Float16)b;
    return (uint)__builtin_bit_cast(ushort, ha) | ((uint)__builtin_bit_cast(ushort, hb) << 16);
}
static __device__ __forceinline__ float h2f(ushort u) {
    return (float)__builtin_bit_cast(_Float16, u);
}
static __device__ __forceinline__ void barrier_lgkm() {
    asm volatile("s_waitcnt lgkmcnt(0)" ::: "memory");
    __builtin_amdgcn_s_barrier();
}

// ---------------------------------------------------------------------------
// Kernel 1: TT projections q,k,v + L2-normalize q,k per head-row.
// Outputs: qq_b bf16 [NH][64] row-major; kqT f16 [64][NH]; vvT f16 [64][NH].
// (identical to r15, verified; 2048 blocks -> 8 blocks/CU of TLP beats the
//  r16 weight-hoist variant, which serialized rows and regressed)
// ---------------------------------------------------------------------------
__global__ __launch_bounds__(256) void proj_qkv(
    const float* __restrict__ x,
    const float* __restrict__ qA, const float* __restrict__ qB, const float* __restrict__ qb,
    const float* __restrict__ kA, const float* __restrict__ kB, const float* __restrict__ kb,
    const float* __restrict__ vA, const float* __restrict__ vB, const float* __restrict__ vb,
    ushort* __restrict__ qq_b, ushort* __restrict__ kqT, ushort* __restrict__ vvT)
{
    __shared__ float qrow[DIM], krow[DIM], vrowS[DIM];
    __shared__ float wred[4][12];
    __shared__ float tvals[12];
    __shared__ float norms[16];

    const int n = blockIdx.x, t = threadIdx.x;
    const int wid = t >> 6, lane = t & 63;

    const float x0 = x[n * DIM + t];
    const float x1 = x[n * DIM + t + 256];

    float p[12];
    #pragma unroll
    for (int r = 0; r < 4; ++r) {
        p[r]     = x0 * qB[r * DIM + t] + x1 * qB[r * DIM + t + 256];
        p[4 + r] = x0 * kB[r * DIM + t] + x1 * kB[r * DIM + t + 256];
        p[8 + r] = x0 * vB[r * DIM + t] + x1 * vB[r * DIM + t + 256];
    }
    #pragma unroll
    for (int i = 0; i < 12; ++i) {
        #pragma unroll
        for (int off = 32; off; off >>= 1) p[i] += __shfl_xor(p[i], off);
    }
    if (lane == 0) {
        #pragma unroll
        for (int i = 0; i < 12; ++i) wred[wid][i] = p[i];
    }
    __syncthreads();
    if (t < 12) tvals[t] = wred[0][t] + wred[1][t] + wred[2][t] + wred[3][t];
    __syncthreads();

    float tq[4], tk[4], tv[4];
    #pragma unroll
    for (int r = 0; r < 4; ++r) { tq[r] = tvals[r]; tk[r] = tvals[4 + r]; tv[r] = tvals[8 + r]; }

    #pragma unroll
    for (int h = 0; h < 2; ++h) {
        const int o = t + h * 256;
        float yq = qb[o], yk = kb[o], yv = vb[o];
        #pragma unroll
        for (int r = 0; r < 4; ++r) {
            yq += tq[r] * qA[o * RANK + r];
            yk += tk[r] * kA[o * RANK + r];
            yv += tv[r] * vA[o * RANK + r];
        }
        qrow[o] = yq; krow[o] = yk; vrowS[o] = yv;
    }
    __syncthreads();

    {
        const int c = t >> 5, i2 = t & 31;
        const float a  = qrow[c * 64 + i2], b2 = qrow[c * 64 + i2 + 32];
        const float ak = krow[c * 64 + i2], bk = krow[c * 64 + i2 + 32];
        float s  = a * a + b2 * b2;
        float sk = ak * ak + bk * bk;
        #pragma unroll
        for (int off = 16; off; off >>= 1) { s += __shfl_xor(s, off); sk += __shfl_xor(sk, off); }
        if (i2 == 0) { norms[c] = sqrtf(s); norms[8 + c] = sqrtf(sk); }
    }
    __syncthreads();

    #pragma unroll
    for (int h = 0; h < 2; ++h) {
        const int o = t + h * 256;
        const int c = o >> 6;
        qq_b[n * DIM + o] = f2bf(qrow[o] / (norms[c] + EPS));
    }

    // transposes: kqT[d][n*8+j] = khat, vvT[d][n*8+j] = v  (f16)
    if (t < 64) {
        uint pk[4], pv[4];
        #pragma unroll
        for (int i = 0; i < 4; ++i) {
            const float k0 = krow[(2 * i) * 64 + t]     / (norms[8 + 2 * i] + EPS);
            const float k1 = krow[(2 * i + 1) * 64 + t] / (norms[8 + 2 * i + 1] + EPS);
            pk[i] = pkh2(k0, k1);
            pv[i] = pkh2(vrowS[(2 * i) * 64 + t], vrowS[(2 * i + 1) * 64 + t]);
        }
        uint4 uk; uk.x = pk[0]; uk.y = pk[1]; uk.z = pk[2]; uk.w = pk[3];
        uint4 uv; uv.x = pv[0]; uv.y = pv[1]; uv.z = pv[2]; uv.w = pv[3];
        *(uint4*)((char*)kqT + (size_t)t * (NH * 2) + (size_t)n * 16) = uk;
        *(uint4*)((char*)vvT + (size_t)t * (NH * 2) + (size_t)n * 16) = uv;
    }
}

// ---------------------------------------------------------------------------
// Kernel 2 (phase A): moment tensors; M1 fused into agroup0/wave0 (verified
// r14/r15). Grid = 512 exactly (16 agroups x 32 ksplits): no straggler tail.
//   T2[a][b][d] = sum_j khat[a]khat[b]v[d];  M1[b][d] = sum_j khat[b]v[d]
// ---------------------------------------------------------------------------
__global__ __launch_bounds__(256, 2) void phaseA(
    const ushort* __restrict__ kqT, const ushort* __restrict__ vvT,
    ushort* __restrict__ partA, ushort* __restrict__ partM1)
{
    __shared__ __align__(16) char smem[2][10240];   // [buf][ K 5120 | V 5120 ]
    constexpr int NSTA = 16;                        // 512 keys / 32

    const int t = threadIdx.x;
    const int w = t >> 6, l = t & 63;
    const int l31 = l & 31, hi = l >> 5;
    const int agroup = blockIdx.x >> 5;             // 0..15
    const int ksplit = blockIdx.x & 31;
    const int kbase = ksplit * 512;
    const int a = agroup * 4 + w;
    const bool doM1 = (agroup == 0) && (w == 0);

    const int srow = t >> 2, sslot = t & 3;
    const int woff = srow * 80 + sslot * 16;
    const size_t go = (size_t)srow * NH + kbase + sslot * 8;

    f32x16 acc[2][2], accM[2][2];
    #pragma unroll
    for (int bt = 0; bt < 2; ++bt)
        #pragma unroll
        for (int dt = 0; dt < 2; ++dt)
            #pragma unroll
            for (int r = 0; r < 16; ++r) { acc[bt][dt][r] = 0.f; accM[bt][dt][r] = 0.f; }

    uint4 kst = *(const uint4*)(kqT + go);
    uint4 vst = *(const uint4*)(vvT + go);
    *(uint4*)(smem[0] + woff) = kst;
    *(uint4*)(smem[0] + 5120 + woff) = vst;
    kst = *(const uint4*)(kqT + go + 32);
    vst = *(const uint4*)(vvT + go + 32);
    barrier_lgkm();

    for (int s = 0; s < NSTA; ++s) {
        const char* B = smem[s & 1];
        if (s + 1 < NSTA) {
            char* D = (char*)smem[(s & 1) ^ 1];
            *(uint4*)(D + woff) = kst;
            *(uint4*)(D + 5120 + woff) = vst;
        }
        if (s + 2 < NSTA) {
            kst = *(const uint4*)(kqT + go + (size_t)(s + 2) * 32);
            vst = *(const uint4*)(vvT + go + (size_t)(s + 2) * 32);
        }

        half8 kraw[2][2], af[2][2], vf[2][2];
        const half8 bc0 = *(const half8*)(B + a * 80 + hi * 16);
        const half8 bc1 = *(const half8*)(B + a * 80 + 32 + hi * 16);
        #pragma unroll
        for (int bt = 0; bt < 2; ++bt) {
            kraw[bt][0] = *(const half8*)(B + (bt * 32 + l31) * 80 + hi * 16);
            kraw[bt][1] = *(const half8*)(B + (bt * 32 + l31) * 80 + 32 + hi * 16);
            af[bt][0] = kraw[bt][0] * bc0;
            af[bt][1] = kraw[bt][1] * bc1;
        }
        #pragma unroll
        for (int dt = 0; dt < 2; ++dt) {
            vf[dt][0] = *(const half8*)(B + 5120 + (dt * 32 + l31) * 80 + hi * 16);
            vf[dt][1] = *(const half8*)(B + 5120 + (dt * 32 + l31) * 80 + 32 + hi * 16);
        }
        #pragma unroll
        for (int bt = 0; bt < 2; ++bt)
            #pragma unroll
            for (int dt = 0; dt < 2; ++dt) {
                acc[bt][dt] = __builtin_amdgcn_mfma_f32_32x32x16_f16(af[bt][0], vf[dt][0], acc[bt][dt], 0, 0, 0);
                acc[bt][dt] = __builtin_amdgcn_mfma_f32_32x32x16_f16(af[bt][1], vf[dt][1], acc[bt][dt], 0, 0, 0);
            }
        if (doM1) {
            #pragma unroll
            for (int bt = 0; bt < 2; ++bt)
                #pragma unroll
                for (int dt = 0; dt < 2; ++dt) {
                    accM[bt][dt] = __builtin_amdgcn_mfma_f32_32x32x16_f16(kraw[bt][0], vf[dt][0], accM[bt][dt], 0, 0, 0);
                    accM[bt][dt] = __builtin_amdgcn_mfma_f32_32x32x16_f16(kraw[bt][1], vf[dt][1], accM[bt][dt], 0, 0, 0);
                }
        }
        barrier_lgkm();
    }

    {
        ushort* dst = partA + ((size_t)(ksplit * 64 + a)) * 4096;
        #pragma unroll
        for (int bt = 0; bt < 2; ++bt)
            #pragma unroll
            for (int dt = 0; dt < 2; ++dt) {
                const int d = dt * 32 + l31;
                #pragma unroll
                for (int g = 0; g < 4; ++g) {
                    uint2 u2;
                    u2.x = pkh2(acc[bt][dt][4 * g],     acc[bt][dt][4 * g + 1]);
                    u2.y = pkh2(acc[bt][dt][4 * g + 2], acc[bt][dt][4 * g + 3]);
                    const int b0 = bt * 32 + 8 * g + 4 * hi;
                    *(uint2*)(dst + (size_t)d * 64 + b0) = u2;
                }
            }
    }
    if (doM1) {
        ushort* dstM = partM1 + (size_t)ksplit * 4096;
        #pragma unroll
        for (int bt = 0; bt < 2; ++bt)
            #pragma unroll
            for (int dt = 0; dt < 2; ++dt) {
                const int d = dt * 32 + l31;
                #pragma unroll
                for (int g = 0; g < 4; ++g) {
                    uint2 u2;
                    u2.x = pkh2(accM[bt][dt][4 * g],     accM[bt][dt][4 * g + 1]);
                    u2.y = pkh2(accM[bt][dt][4 * g + 2], accM[bt][dt][4 * g + 3]);
                    const int b0 = bt * 32 + 8 * g + 4 * hi;
                    *(uint2*)(dstM + (size_t)d * 64 + b0) = u2;
                }
            }
    }
}

// ---------------------------------------------------------------------------
// Kernel 3: parallel reduction of partials (identical to r15, verified;
// 260 blocks of uint2-granular work beat the r16 130-block uint4 variant).
// ---------------------------------------------------------------------------
__global__ __launch_bounds__(256) void reduce_mom(
    const ushort* __restrict__ partA, const ushort* __restrict__ partM1,
    ushort* __restrict__ T2s, ushort* __restrict__ M1s, float* __restrict__ Vpart)
{
    const int blk = blockIdx.x, t = threadIdx.x;
    if (blk < 256) {
        const int g = blk * 256 + t;
        const uint2* src = (const uint2*)partA;
        float s0 = 0.f, s1 = 0.f, s2 = 0.f, s3 = 0.f;
        #pragma unroll
        for (int ks = 0; ks < KSPL; ++ks) {
            const uint2 u = src[(size_t)ks * 65536 + g];
            s0 += h2f((ushort)(u.x & 0xffff));
            s1 += h2f((ushort)(u.x >> 16));
            s2 += h2f((ushort)(u.y & 0xffff));
            s3 += h2f((ushort)(u.y >> 16));
        }
        uint2 o;
        o.x = (uint)f2bf(C2 * s0) | ((uint)f2bf(C2 * s1) << 16);
        o.y = (uint)f2bf(C2 * s2) | ((uint)f2bf(C2 * s3) << 16);
        ((uint2*)T2s)[g] = o;
        const int a  = g >> 10;
        const int d  = (g >> 4) & 63;
        const int b0 = (g & 15) * 4;
        if (a >= b0 && a < b0 + 4) {
            const int r = a - b0;
            const float sd = (r == 0) ? s0 : (r == 1) ? s1 : (r == 2) ? s2 : s3;
            Vpart[a * 64 + d] = sd;
        }
    } else {
        const int g = (blk - 256) * 256 + t;
        const uint2* src = (const uint2*)partM1;
        float s0 = 0.f, s1 = 0.f, s2 = 0.f, s3 = 0.f;
        #pragma unroll
        for (int ks = 0; ks < KSPL; ++ks) {
            const uint2 u = src[(size_t)ks * 1024 + g];
            s0 += h2f((ushort)(u.x & 0xffff));
            s1 += h2f((ushort)(u.x >> 16));
            s2 += h2f((ushort)(u.y & 0xffff));
            s3 += h2f((ushort)(u.y >> 16));
        }
        uint2 o;
        o.x = (uint)f2bf(C1 * s0) | ((uint)f2bf(C1 * s1) << 16);
        o.y = (uint)f2bf(C1 * s2) | ((uint)f2bf(C1 * s3) << 16);
        ((uint2*)M1s)[g] = o;
    }
}

// ---------------------------------------------------------------------------
// Kernel 4 (phase B, fused finalize): identical to r15, verified.
// ---------------------------------------------------------------------------
__global__ __launch_bounds__(256, 3) void phaseB(
    const ushort* __restrict__ qq_b, const ushort* __restrict__ T2s,
    const ushort* __restrict__ M1s, const float* __restrict__ Vpart,
    const float* __restrict__ oA, const float* __restrict__ oB,
    const float* __restrict__ ob, float* __restrict__ out)
{
    __shared__ float Lred[4][64][33];   // [wave][d][q] padded -> conflict-free
    __shared__ float anum[32][65];      // [q][d] measure values
    __shared__ float VsumL[64];

    const int t = threadIdx.x;
    const int w = t >> 6, l = t & 63;
    const int l31 = l & 31, hi = l >> 5;
    const int q0 = blockIdx.x * 32;
    const int n0 = q0 >> 3;             // first of 4 (b,s) rows

    if (w == 3) {
        float vs = 0.f;
        #pragma unroll
        for (int a2 = 0; a2 < 64; ++a2) vs += Vpart[a2 * 64 + l];
        VsumL[l] = vs;
    }

    bf16x8 Qf[4];
    #pragma unroll
    for (int w16 = 0; w16 < 4; ++w16)
        Qf[w16] = *(const bf16x8*)((const char*)qq_b
            + (size_t)(q0 + l31) * 128 + w16 * 32 + hi * 16);

    float sv[16];
    {
        const uint4 u0 = *(const uint4*)(qq_b + (size_t)(q0 + l31) * 64 + w * 16);
        const uint4 u1 = *(const uint4*)(qq_b + (size_t)(q0 + l31) * 64 + w * 16 + 8);
        sv[0] = bf2f((ushort)(u0.x & 0xffff)); sv[1] = bf2f((ushort)(u0.x >> 16));
        sv[2] = bf2f((ushort)(u0.y & 0xffff)); sv[3] = bf2f((ushort)(u0.y >> 16));
        sv[4] = bf2f((ushort)(u0.z & 0xffff)); sv[5] = bf2f((ushort)(u0.z >> 16));
        sv[6] = bf2f((ushort)(u0.w & 0xffff)); sv[7] = bf2f((ushort)(u0.w >> 16));
        sv[8]  = bf2f((ushort)(u1.x & 0xffff)); sv[9]  = bf2f((ushort)(u1.x >> 16));
        sv[10] = bf2f((ushort)(u1.y & 0xffff)); sv[11] = bf2f((ushort)(u1.y >> 16));
        sv[12] = bf2f((ushort)(u1.z & 0xffff)); sv[13] = bf2f((ushort)(u1.z >> 16));
        sv[14] = bf2f((ushort)(u1.w & 0xffff)); sv[15] = bf2f((ushort)(u1.w >> 16));
    }

    f32x16 acc[2];
    #pragma unroll
    for (int dt = 0; dt < 2; ++dt)
        #pragma unroll
        for (int r = 0; r < 16; ++r) acc[dt][r] = 0.f;

    #pragma unroll 2
    for (int ai = 0; ai < 16; ++ai) {
        const char* base = (const char*)(T2s + (size_t)(w * 16 + ai) * 4096);
        #pragma unroll
        for (int dt = 0; dt < 2; ++dt) {
            bf16x8 af[4];
            #pragma unroll
            for (int w16 = 0; w16 < 4; ++w16)
                af[w16] = *(const bf16x8*)(base + (dt * 32 + l31) * 128 + w16 * 32 + hi * 16);
            f32x16 st;
            #pragma unroll
            for (int r = 0; r < 16; ++r) st[r] = 0.f;
            #pragma unroll
            for (int w16 = 0; w16 < 4; ++w16)
                st = __builtin_amdgcn_mfma_f32_32x32x16_bf16(af[w16], Qf[w16], st, 0, 0, 0);
            #pragma unroll
            for (int r = 0; r < 16; ++r)
                acc[dt][r] = fmaf(sv[ai], st[r], acc[dt][r]);
        }
    }

    if (w == 0) {
        #pragma unroll
        for (int dt = 0; dt < 2; ++dt) {
            bf16x8 af[4];
            #pragma unroll
            for (int w16 = 0; w16 < 4; ++w16)
                af[w16] = *(const bf16x8*)((const char*)M1s + (dt * 32 + l31) * 128 + w16 * 32 + hi * 16);
            f32x16 st;
            #pragma unroll
            for (int r = 0; r < 16; ++r) st[r] = 0.f;
            #pragma unroll
            for (int w16 = 0; w16 < 4; ++w16)
                st = __builtin_amdgcn_mfma_f32_32x32x16_bf16(af[w16], Qf[w16], st, 0, 0, 0);
            #pragma unroll
            for (int r = 0; r < 16; ++r) acc[dt][r] += st[r];
        }
    }

    #pragma unroll
    for (int dt = 0; dt < 2; ++dt)
        #pragma unroll
        for (int r = 0; r < 16; ++r) {
            const int d = dt * 32 + 8 * (r >> 2) + 4 * hi + (r & 3);
            Lred[w][d][l31] = acc[dt][r];
        }
    __syncthreads();

    {
        const int q = t >> 3, db = (t & 7) * 8;
        float av[8];
        float ss = 0.f;
        #pragma unroll
        for (int i = 0; i < 8; ++i) {
            const int d = db + i;
            const float s = (Lred[0][d][q] + Lred[1][d][q])
                          + (Lred[2][d][q] + Lred[3][d][q]) + VsumL[d];
            av[i] = s;
            ss = fmaf(s, s, ss);
        }
        ss += __shfl_xor(ss, 1);
        ss += __shfl_xor(ss, 2);
        ss += __shfl_xor(ss, 4);
        const float inv = 1.f / (ss + EPSDEN2);
        #pragma unroll
        for (int i = 0; i < 8; ++i) anum[q][db + i] = av[i] * av[i] * inv;
    }
    __syncthreads();

    {
        float p0 = 0.f, p1 = 0.f, p2 = 0.f, p3 = 0.f;
        #pragma unroll
        for (int h2 = 0; h2 < 8; ++h2) {
            const int o = h2 * 64 + l;
            const float m = anum[w * 8 + h2][l];
            p0 = fmaf(m, oB[o],        p0);
            p1 = fmaf(m, oB[512 + o],  p1);
            p2 = fmaf(m, oB[1024 + o], p2);
            p3 = fmaf(m, oB[1536 + o], p3);
        }
        #pragma unroll
        for (int off = 32; off; off >>= 1) {
            p0 += __shfl_xor(p0, off);
            p1 += __shfl_xor(p1, off);
            p2 += __shfl_xor(p2, off);
            p3 += __shfl_xor(p3, off);
        }
        float* dstrow = out + (size_t)(n0 + w) * DIM;
        #pragma unroll
        for (int h2 = 0; h2 < 8; ++h2) {
            const int o = h2 * 64 + l;
            const float4 a4 = *(const float4*)(oA + o * RANK);
            dstrow[o] = ob[o] + p0 * a4.x + p1 * a4.y + p2 * a4.z + p3 * a4.w;
        }
    }
}

// ---------------------------------------------------------------------------
extern "C" void kernel_launch(void* const* d_in, const int* in_sizes, int n_in,
                              void* d_out, int out_size, void* d_ws, size_t ws_size,
                              hipStream_t stream) {
    const float* x  = (const float*)d_in[0];
    const float* qA = (const float*)d_in[1];
    const float* qB = (const float*)d_in[2];
    const float* qb = (const float*)d_in[3];
    const float* kA = (const float*)d_in[4];
    const float* kB = (const float*)d_in[5];
    const float* kb = (const float*)d_in[6];
    const float* vA = (const float*)d_in[7];
    const float* vB = (const float*)d_in[8];
    const float* vb = (const float*)d_in[9];
    const float* oA = (const float*)d_in[10];
    const float* oB = (const float*)d_in[11];
    const float* ob = (const float*)d_in[12];

    // ws: qq 2MB | kqT 2MB | vvT 2MB | T2s 512KB | M1s 8KB | partM1 256KB |
    //     Vpart 16KB | partA 16MB
    ushort* qq_b   = (ushort*)d_ws;
    ushort* kqT    = qq_b + (size_t)NH * DH;
    ushort* vvT    = kqT + (size_t)NH * DH;
    ushort* T2s    = vvT + (size_t)NH * DH;
    ushort* M1s    = T2s + (size_t)64 * 4096;
    ushort* partM1 = M1s + 4096;
    float*  Vpart  = (float*)(partM1 + (size_t)KSPL * 4096);
    ushort* partA  = (ushort*)(Vpart + 4096);

    float* out = (float*)d_out;

    proj_qkv<<<NROW, 256, 0, stream>>>(x, qA, qB, qb, kA, kB, kb, vA, vB, vb, qq_b, kqT, vvT);
    phaseA<<<512, 256, 0, stream>>>(kqT, vvT, partA, partM1);
    reduce_mom<<<260, 256, 0, stream>>>(partA, partM1, T2s, M1s, Vpart);
    phaseB<<<512, 256, 0, stream>>>(qq_b, T2s, M1s, Vpart, oA, oB, ob, out);
}